// Round 12
// baseline (87.287 us; speedup 1.0000x reference)
//
#include <hip/hip_runtime.h>
#include <hip/hip_bf16.h>

#define S_   8
#define N_   1024
#define KG_  16
#define MW_  64
#define CI_  128
#define CO_  256

typedef __attribute__((ext_vector_type(8))) short bf16x8;
typedef __attribute__((ext_vector_type(4))) float f32x4;

// ---------------------------------------------------------------------------
// Fused: W fp32->bf16 convert + circular sliding-window sums (bf16 out).
// win2[s][t][c] = win2[s][t+1024][c] = sum_{m<64} x[s][(t+m)%N][c]
// Output DUPLICATED across 2N rows so the GEMM needs no circular wrap.
// ---------------------------------------------------------------------------
__global__ __launch_bounds__(256) void win_kernel(const float* __restrict__ x,
                                                  const float* __restrict__ W,
                                                  __hip_bfloat16* __restrict__ win,
                                                  __hip_bfloat16* __restrict__ Wb) {
    __shared__ float lds[96][CI_];           // 48 KB
    const int b   = blockIdx.x;              // 0..255
    const int tid = threadIdx.x;

    // --- W conversion: 8 elems per thread ---
    {
        const int wi = (b * 256 + tid) * 8;
        const float4 v0 = *(const float4*)&W[wi];
        const float4 v1 = *(const float4*)&W[wi + 4];
        union { unsigned short u[8]; uint4 v; } o;
        __hip_bfloat16 h;
        h = __float2bfloat16(v0.x); o.u[0] = *(unsigned short*)&h;
        h = __float2bfloat16(v0.y); o.u[1] = *(unsigned short*)&h;
        h = __float2bfloat16(v0.z); o.u[2] = *(unsigned short*)&h;
        h = __float2bfloat16(v0.w); o.u[3] = *(unsigned short*)&h;
        h = __float2bfloat16(v1.x); o.u[4] = *(unsigned short*)&h;
        h = __float2bfloat16(v1.y); o.u[5] = *(unsigned short*)&h;
        h = __float2bfloat16(v1.z); o.u[6] = *(unsigned short*)&h;
        h = __float2bfloat16(v1.w); o.u[7] = *(unsigned short*)&h;
        *(uint4*)&Wb[wi] = o.v;
    }

    // --- sliding window ---
    const int s   = b >> 5;
    const int t0  = (b & 31) << 5;           // 32 t's per block
    const float* xs = x + (size_t)s * N_ * CI_;

    for (int e = tid * 4; e < 96 * CI_; e += 256 * 4) {
        const int r = e >> 7;
        const int c = e & (CI_ - 1);
        *(float4*)&lds[r][c] = *(const float4*)&xs[((t0 + r) & (N_ - 1)) * CI_ + c];
    }
    __syncthreads();

    const int c  = tid & (CI_ - 1);
    const int tb = (tid >> 7) << 4;          // 0 or 16
    float s0 = 0.f, s1 = 0.f, s2 = 0.f, s3 = 0.f;
    #pragma unroll
    for (int m = 0; m < MW_; m += 4) {
        s0 += lds[tb + m + 0][c];
        s1 += lds[tb + m + 1][c];
        s2 += lds[tb + m + 2][c];
        s3 += lds[tb + m + 3][c];
    }
    float w = (s0 + s1) + (s2 + s3);
    __hip_bfloat16* wo = win + (size_t)s * (2 * N_) * CI_;
    {
        const int row = t0 + tb;
        const __hip_bfloat16 hv = __float2bfloat16(w);
        wo[row * CI_ + c] = hv;
        wo[(row + N_) * CI_ + c] = hv;
    }
    #pragma unroll
    for (int t = 1; t < 16; ++t) {
        w += lds[tb + t - 1 + MW_][c] - lds[tb + t - 1][c];
        const int row = t0 + tb + t;
        const __hip_bfloat16 hv = __float2bfloat16(w);
        wo[row * CI_ + c] = hv;
        wo[(row + N_) * CI_ + c] = hv;
    }
}

// ---------------------------------------------------------------------------
// out[s,n,o] = sum_{g,c} win2[s,n+64g,c] * W[g,o,c]
// SINGLE-WAVE, BARRIER-FREE LDS MFMA GEMM (r10/r11 PMC-driven redesign:
// blocks/CU is the dominant variable; barrier-locked waves don't overlap).
// Block = 1 wave (64 thr). Wave owns a 32x32 output tile (2x2 frags of
// 16x16x32 bf16). BK=64, 32 K-steps. LDS [2][32][64] A + B = 16 KB dbuf
// -> 8 fully independent blocks/CU (grid 2048, XCD-pinned s = blk&7).
// The wave stages its own tiles (8 global_load_lds/step) and self-orders
// with counted vmcnt(8) ONLY — zero s_barrier in the whole kernel.
// Swizzle/fragment/D-layout algebra identical to validated r10/r11.
// ---------------------------------------------------------------------------
#define KSTEPS 32
#define ATILE 2048              // 32 rows x 64 elems
#define BTILE 2048

__global__ __launch_bounds__(64, 2) void gemm_kernel(const __hip_bfloat16* __restrict__ winb,
                                                     const __hip_bfloat16* __restrict__ Wb,
                                                     float* __restrict__ out) {
    __shared__ __align__(16) unsigned short Alds[2 * ATILE];   // 8 KB
    __shared__ __align__(16) unsigned short Blds[2 * BTILE];   // 8 KB

    const int l   = threadIdx.x;             // 0..63
    const int s   = blockIdx.x & 7;          // XCD-pinned sample index
    const int rem = blockIdx.x >> 3;         // 0..255
    const int n0  = (rem & 31) << 5;         // 32-row tile
    const int o0  = (rem >> 5) << 5;         // 32-col tile

    const int fr = l & 15;
    const int kq = l >> 4;                   // 0..3
    const int rl = l >> 3;                   // staging: row within 8-row chunk
    const int ps = l & 7;                    // staging: physical 16B slot

    const unsigned short* winp = (const unsigned short*)winb
                               + ((size_t)s * 2 * N_ + n0) * CI_;
    const unsigned short* Wp   = (const unsigned short*)Wb;

    f32x4 acc[2][2];
    #pragma unroll
    for (int i = 0; i < 2; ++i)
        #pragma unroll
        for (int j = 0; j < 2; ++j)
            acc[i][j] = f32x4{0.f, 0.f, 0.f, 0.f};

    // Stage step t into buffer buf: A 4 chunks of 1KB + B 4 chunks; 8 loads.
    auto stage = [&](int t, int buf) {
        const int g  = t >> 1;
        const int ch = (t & 1) << 6;         // K half within the group
        unsigned short* Ab = Alds + buf * ATILE;
        unsigned short* Bb = Blds + buf * BTILE;
        #pragma unroll
        for (int q = 0; q < 4; ++q) {
            const int row = q * 8 + rl;      // 0..31
            const int ss  = ps ^ (row & 7);
            const unsigned short* src = winp + (g * MW_ + row) * CI_ + ch + ss * 8;
            __builtin_amdgcn_global_load_lds((const __attribute__((address_space(1))) void*)src,
                                             (__attribute__((address_space(3))) void*)(Ab + (q * 8) * 64),
                                             16, 0, 0);
        }
        #pragma unroll
        for (int q = 0; q < 4; ++q) {
            const int row = q * 8 + rl;      // o index 0..31
            const int ss  = ps ^ (row & 7);
            const unsigned short* src = Wp + ((g * CO_ + o0 + row) * CI_) + ch + ss * 8;
            __builtin_amdgcn_global_load_lds((const __attribute__((address_space(1))) void*)src,
                                             (__attribute__((address_space(3))) void*)(Bb + (q * 8) * 64),
                                             16, 0, 0);
        }
    };

    stage(0, 0);                             // 8 loads in flight

    for (int t = 0; t < KSTEPS; ++t) {
        const int cur = t & 1;
        if (t < KSTEPS - 1) {
            stage(t + 1, cur ^ 1);           // +8 -> 16 in flight
            asm volatile("s_waitcnt vmcnt(8)" ::: "memory");   // tile t done
        } else {
            asm volatile("s_waitcnt vmcnt(0)" ::: "memory");
        }
        __builtin_amdgcn_sched_barrier(0);   // no s_barrier: single wave

        const unsigned short* Ab = Alds + cur * ATILE;
        const unsigned short* Bb = Blds + cur * BTILE;
        #pragma unroll
        for (int ks = 0; ks < 2; ++ks) {
            const int sl = ks * 4 + kq;      // logical 16B slot 0..7
            bf16x8 af[2], bfg[2];
            #pragma unroll
            for (int i = 0; i < 2; ++i) {
                const int ar = i * 16 + fr;
                af[i] = *(const bf16x8*)&Ab[ar * 64 + ((sl ^ (ar & 7)) * 8)];
            }
            #pragma unroll
            for (int j = 0; j < 2; ++j) {
                const int br = j * 16 + fr;
                bfg[j] = *(const bf16x8*)&Bb[br * 64 + ((sl ^ (br & 7)) * 8)];
            }
            #pragma unroll
            for (int i = 0; i < 2; ++i)
                #pragma unroll
                for (int j = 0; j < 2; ++j)
                    acc[i][j] = __builtin_amdgcn_mfma_f32_16x16x32_bf16(af[i], bfg[j], acc[i][j], 0, 0, 0);
        }
        __builtin_amdgcn_sched_barrier(0);   // keep ds_reads above next stage
    }

    // D layout: col = lane&15, row = (lane>>4)*4 + reg (validated r2-r11)
    float* op = out + ((size_t)(s * N_ + n0) * CO_) + o0;
    #pragma unroll
    for (int i = 0; i < 2; ++i)
        #pragma unroll
        for (int j = 0; j < 2; ++j)
            #pragma unroll
            for (int r = 0; r < 4; ++r)
                op[(i * 16 + kq * 4 + r) * CO_ + j * 16 + fr] = acc[i][j][r];
}

extern "C" void kernel_launch(void* const* d_in, const int* in_sizes, int n_in,
                              void* d_out, int out_size, void* d_ws, size_t ws_size,
                              hipStream_t stream) {
    const float* x = (const float*)d_in[0];   // [S, N, CI]
    const float* W = (const float*)d_in[1];   // [K, CO, CI]

    __hip_bfloat16* winb = (__hip_bfloat16*)d_ws;                               // 4 MB (2N rows)
    __hip_bfloat16* Wbb  = (__hip_bfloat16*)((char*)d_ws +
                              (size_t)S_ * 2 * N_ * CI_ * sizeof(__hip_bfloat16)); // 1 MB
    float* out = (float*)d_out;               // [S, N, CO] fp32

    win_kernel<<<256, 256, 0, stream>>>(x, W, winb, Wbb);
    gemm_kernel<<<2048, 64, 0, stream>>>(winb, Wbb, out);
}